// Round 1
// baseline (801.321 us; speedup 1.0000x reference)
//
#include <hip/hip_runtime.h>

// Problem dims (fixed by setup_inputs)
constexpr int N_ = 6;            // B*N views
constexpr int C_ = 64;           // channels
constexpr int D0 = 48;           // W  (grid z-coord axis)
constexpr int D1 = 32;           // H  (grid y-coord axis)
constexpr int D2 = 88;           // D  (grid x-coord axis, innermost)
constexpr int P_ = D0 * D1 * D2; // 135168 spatial positions per view
constexpr int Z_ = 16, Y_ = 160, X_ = 160;

// ---------------------------------------------------------------------------
// Kernel A: transpose features (n, c, p) -> (n, p, c) so that the 64 channels
// of one spatial position are contiguous (256 B). One block does a 64p x 64c
// tile via padded LDS; reads and writes both coalesced.
// ---------------------------------------------------------------------------
__global__ __launch_bounds__(256) void k_transpose(const float* __restrict__ in,
                                                   float* __restrict__ out) {
    __shared__ float lds[64][65];
    const int n  = blockIdx.y;
    const int p0 = blockIdx.x * 64;
    const int tx = threadIdx.x;   // 0..63
    const int ty = threadIdx.y;   // 0..3
    const float* ip = in  + (size_t)n * C_ * P_;
    float*       op = out + (size_t)n * P_ * C_;
#pragma unroll
    for (int i = 0; i < 16; ++i) {
        int c = i * 4 + ty;
        lds[tx][c] = ip[(size_t)c * P_ + p0 + tx];   // coalesced along p
    }
    __syncthreads();
#pragma unroll
    for (int i = 0; i < 16; ++i) {
        int pl = i * 4 + ty;
        op[(size_t)(p0 + pl) * C_ + tx] = lds[pl][tx];  // coalesced along c
    }
}

// ---------------------------------------------------------------------------
// Kernel B: trilinear gather + mask + view-sum + transposed write.
// Block = 256 threads = 4 waves. Wave w handles y = y0+w, all 16 z, at fixed
// x; lane = channel. Each corner gather is one coalesced 256 B transaction
// (channel-last layout). Epilogue transposes 64pt x 64ch through LDS so the
// (C,X,Y,Z) output is written in 256 B coalesced runs.
// LS = channel stride in the feature buffer (C_ for transposed, 1 for raw
// layout fallback when ws is too small).
// ---------------------------------------------------------------------------
template <int LS>
__global__ __launch_bounds__(256) void k_sample(const float* __restrict__ feat,
                                                const float* __restrict__ grid,
                                                const int* __restrict__ mask,
                                                float* __restrict__ outp) {
    const int x    = blockIdx.x;       // 0..X_-1
    const int y0   = blockIdx.y * 4;   // y tile base
    const int lane = threadIdx.x;      // channel
    const int w    = threadIdx.y;      // 0..3
    const int y    = y0 + w;

    float acc[16];
#pragma unroll
    for (int i = 0; i < 16; ++i) acc[i] = 0.f;

    for (int n = 0; n < N_; ++n) {
        // base pointer for this (view, channel)
        const float* fb = (LS == C_) ? (feat + (size_t)n * P_ * C_ + lane)
                                     : (feat + ((size_t)n * C_ + lane) * P_);
        for (int z = 0; z < Z_; ++z) {
            const int pidx = ((n * Z_ + z) * Y_ + y) * X_ + x;
            if (mask[pidx]) continue;                    // wave-uniform skip
            const float* g = grid + (size_t)pidx * 3;    // uniform addr -> bcast
            const float gx = (g[0] + 1.f) * (0.5f * (D2 - 1));
            const float gy = (g[1] + 1.f) * (0.5f * (D1 - 1));
            const float gz = (g[2] + 1.f) * (0.5f * (D0 - 1));
            const float fx = floorf(gx), fy = floorf(gy), fz = floorf(gz);
            const float tx = gx - fx, ty = gy - fy, tz = gz - fz;
            const int x0 = (int)fx, y0i = (int)fy, z0i = (int)fz;
            const int x1 = x0 + 1, y1 = y0i + 1, z1 = z0i + 1;
            // fully-outside sample contributes nothing
            if (x1 < 0 || x0 > D2 - 1 || y1 < 0 || y0i > D1 - 1 ||
                z1 < 0 || z0i > D0 - 1) continue;
            // validity folded into the 1-D weights
            const float vx0 = (x0 >= 0)      ? (1.f - tx) : 0.f;
            const float vx1 = (x1 <= D2 - 1) ? tx         : 0.f;
            const float vy0 = (y0i >= 0)     ? (1.f - ty) : 0.f;
            const float vy1 = (y1 <= D1 - 1) ? ty         : 0.f;
            const float vz0 = (z0i >= 0)     ? (1.f - tz) : 0.f;
            const float vz1 = (z1 <= D0 - 1) ? tz         : 0.f;
            const int xc0 = max(x0, 0),  xc1 = min(x1, D2 - 1);
            const int yc0 = max(y0i, 0), yc1 = min(y1, D1 - 1);
            const int zc0 = max(z0i, 0), zc1 = min(z1, D0 - 1);
            const int r00 = (zc0 * D1 + yc0) * D2;
            const int r01 = (zc0 * D1 + yc1) * D2;
            const int r10 = (zc1 * D1 + yc0) * D2;
            const int r11 = (zc1 * D1 + yc1) * D2;
            // 8 coalesced gathers (256 B per wave each)
            const float v000 = fb[(size_t)(r00 + xc0) * LS];
            const float v001 = fb[(size_t)(r00 + xc1) * LS];
            const float v010 = fb[(size_t)(r01 + xc0) * LS];
            const float v011 = fb[(size_t)(r01 + xc1) * LS];
            const float v100 = fb[(size_t)(r10 + xc0) * LS];
            const float v101 = fb[(size_t)(r10 + xc1) * LS];
            const float v110 = fb[(size_t)(r11 + xc0) * LS];
            const float v111 = fb[(size_t)(r11 + xc1) * LS];
            const float w00 = vz0 * vy0, w01 = vz0 * vy1;
            const float w10 = vz1 * vy0, w11 = vz1 * vy1;
            acc[z] += (v000 * vx0 + v001 * vx1) * w00
                    + (v010 * vx0 + v011 * vx1) * w01
                    + (v100 * vx0 + v101 * vx1) * w10
                    + (v110 * vx0 + v111 * vx1) * w11;
        }
    }

    // Epilogue: transpose 64 points x 64 channels through LDS, then write
    // coalesced: for fixed (c, x), the 64 points (4y x 16z) are contiguous.
    __shared__ float lds[64][65];
#pragma unroll
    for (int z = 0; z < 16; ++z)
        lds[w * 16 + z][lane] = acc[z];
    __syncthreads();
    const size_t obase = (size_t)y0 * Z_ + (size_t)x * (Y_ * Z_);
#pragma unroll
    for (int i = 0; i < 16; ++i) {
        int c = i * 4 + w;
        outp[(size_t)c * (X_ * Y_ * Z_) + obase + lane] = lds[lane][c];
    }
}

extern "C" void kernel_launch(void* const* d_in, const int* in_sizes, int n_in,
                              void* d_out, int out_size, void* d_ws, size_t ws_size,
                              hipStream_t stream) {
    const float* feat = (const float*)d_in[0];
    const float* grid = (const float*)d_in[1];
    const int*   mask = (const int*)d_in[2];
    float*       outp = (float*)d_out;

    const size_t needed = (size_t)N_ * P_ * C_ * sizeof(float);
    if (ws_size >= needed) {
        float* featT = (float*)d_ws;
        k_transpose<<<dim3(P_ / 64, N_), dim3(64, 4), 0, stream>>>(feat, featT);
        k_sample<C_><<<dim3(X_, Y_ / 4), dim3(64, 4), 0, stream>>>(featT, grid, mask, outp);
    } else {
        // fallback: gather straight from (n, c, p) layout (uncoalesced but correct)
        k_sample<1><<<dim3(X_, Y_ / 4), dim3(64, 4), 0, stream>>>(feat, grid, mask, outp);
    }
}

// Round 2
// 633.322 us; speedup vs baseline: 1.2653x; 1.2653x over previous
//
#include <hip/hip_runtime.h>
#include <hip/hip_fp16.h>

// Problem dims (fixed by setup_inputs)
constexpr int N_ = 6;            // B*N views
constexpr int C_ = 64;           // channels
constexpr int D0 = 48;           // W  (grid z-coord axis)
constexpr int D1 = 32;           // H  (grid y-coord axis)
constexpr int D2 = 88;           // D  (grid x-coord axis, innermost)
constexpr int P_ = D0 * D1 * D2; // 135168 positions per view
constexpr int Z_ = 16, Y_ = 160, X_ = 160;
constexpr int NP_ = N_ * Z_ * Y_ * X_;   // 2,457,600 sample points

__device__ inline unsigned pkh(float a, float b) {
    __half2 h = __floats2half2_rn(a, b);
    return *reinterpret_cast<unsigned*>(&h);
}
__device__ inline float2 uph(unsigned u) {
    __half2 h = *reinterpret_cast<__half2*>(&u);
    return __half22float2(h);
}

// ---------------------------------------------------------------------------
// Kernel A: transpose+convert features (n,c,p) fp32 -> (n,p,c) fp16.
// 64p x 64c tile. Phase 1: float4 loads (coalesced, 4 B-bank-checked LDS
// writes, <=2-way). Phase 2: 8ch half-pack, 16 B stores (1 KB/wave runs).
// ---------------------------------------------------------------------------
__global__ __launch_bounds__(256) void k_transpose_h(const float* __restrict__ in,
                                                     __half* __restrict__ out) {
    __shared__ float lds[64][65];
    const int n  = blockIdx.y;
    const int p0 = blockIdx.x * 64;
    const int t  = threadIdx.x;          // 0..255
    const float* ip = in + (size_t)n * C_ * P_;
    __half*      op = out + (size_t)n * P_ * C_;

    const int pq = t & 15;               // p-quad within tile
    const int cb = t >> 4;               // 0..15
#pragma unroll
    for (int i = 0; i < 4; ++i) {
        const int c = i * 16 + cb;
        const float4 v = *reinterpret_cast<const float4*>(ip + (size_t)c * P_ + p0 + pq * 4);
        lds[pq * 4 + 0][c] = v.x;
        lds[pq * 4 + 1][c] = v.y;
        lds[pq * 4 + 2][c] = v.z;
        lds[pq * 4 + 3][c] = v.w;
    }
    __syncthreads();
    const int c0 = (t & 7) * 8;
    const int pr = t >> 3;               // 0..31
#pragma unroll
    for (int i = 0; i < 2; ++i) {
        const int p = i * 32 + pr;
        uint4 u;
        u.x = pkh(lds[p][c0 + 0], lds[p][c0 + 1]);
        u.y = pkh(lds[p][c0 + 2], lds[p][c0 + 3]);
        u.z = pkh(lds[p][c0 + 4], lds[p][c0 + 5]);
        u.w = pkh(lds[p][c0 + 6], lds[p][c0 + 7]);
        *reinterpret_cast<uint4*>(op + (size_t)(p0 + p) * C_ + c0) = u;
    }
}

// ---------------------------------------------------------------------------
// Kernel B: precompute per sample point: 4 clamped row indices (view-folded,
// 20 bits) + dx + skip flag (mask OR fully outside), and 8 pre-multiplied
// trilinear weights as fp16. 32 B/point, coalesced write.
// ---------------------------------------------------------------------------
__global__ __launch_bounds__(256) void k_pre(const float* __restrict__ grid,
                                             const int* __restrict__ mask,
                                             uint4* __restrict__ S) {
    const int pidx = blockIdx.x * 256 + threadIdx.x;
    const float* g = grid + (size_t)pidx * 3;
    const float gx = (g[0] + 1.f) * (0.5f * (D2 - 1));
    const float gy = (g[1] + 1.f) * (0.5f * (D1 - 1));
    const float gz = (g[2] + 1.f) * (0.5f * (D0 - 1));
    const float fx = floorf(gx), fy = floorf(gy), fz = floorf(gz);
    const float tx = gx - fx, ty = gy - fy, tz = gz - fz;
    const int x0 = (int)fx, y0 = (int)fy, z0 = (int)fz;
    const int x1 = x0 + 1, y1 = y0 + 1, z1 = z0 + 1;
    const bool skip = (mask[pidx] != 0)
                   || x1 < 0 || x0 > D2 - 1 || y1 < 0 || y0 > D1 - 1
                   || z1 < 0 || z0 > D0 - 1;
    const float vx0 = (x0 >= 0)      ? (1.f - tx) : 0.f;
    const float vx1 = (x1 <= D2 - 1) ? tx         : 0.f;
    const float vy0 = (y0 >= 0)      ? (1.f - ty) : 0.f;
    const float vy1 = (y1 <= D1 - 1) ? ty         : 0.f;
    const float vz0 = (z0 >= 0)      ? (1.f - tz) : 0.f;
    const float vz1 = (z1 <= D0 - 1) ? tz         : 0.f;
    const int xc0 = max(x0, 0),  xc1 = min(x1, D2 - 1);
    const int yc0 = max(y0, 0),  yc1 = min(y1, D1 - 1);
    const int zc0 = max(z0, 0),  zc1 = min(z1, D0 - 1);
    const int n = pidx / (Z_ * Y_ * X_);
    const unsigned base = (unsigned)(n * P_);
    const unsigned q00 = base + (zc0 * D1 + yc0) * D2 + xc0;
    const unsigned q01 = base + (zc0 * D1 + yc1) * D2 + xc0;
    const unsigned q10 = base + (zc1 * D1 + yc0) * D2 + xc0;
    const unsigned q11 = base + (zc1 * D1 + yc1) * D2 + xc0;
    const unsigned dx = (unsigned)(xc1 - xc0);           // 0 or 1
    const float w00 = vz0 * vy0, w01 = vz0 * vy1;
    const float w10 = vz1 * vy0, w11 = vz1 * vy1;
    uint4 A = make_uint4(q00 | (dx << 30) | (skip ? 0x80000000u : 0u), q01, q10, q11);
    uint4 B = make_uint4(pkh(vx0 * w00, vx1 * w00), pkh(vx0 * w01, vx1 * w01),
                         pkh(vx0 * w10, vx1 * w10), pkh(vx0 * w11, vx1 * w11));
    S[(size_t)pidx * 2 + 0] = A;
    S[(size_t)pidx * 2 + 1] = B;
}

// ---------------------------------------------------------------------------
// Kernel C: gather + view-sum. lane = channel; wave = one (x,y) column over
// 16 z; per sample: 2 uniform 16 B struct loads (SMEM path), up to 8
// coalesced 128 B fp16 gathers, 8 FMA. Epilogue: LDS transpose -> coalesced
// (C,X,Y,Z) write.
// ---------------------------------------------------------------------------
__global__ __launch_bounds__(256) void k_sample3(const __half* __restrict__ feat,
                                                 const uint4* __restrict__ S,
                                                 float* __restrict__ outp) {
    const int x    = blockIdx.x;       // 0..X_-1
    const int y0   = blockIdx.y * 4;
    const int lane = threadIdx.x;      // channel
    const int wv   = threadIdx.y;      // wave id 0..3
    const int y    = __builtin_amdgcn_readfirstlane(y0 + wv);  // wave-uniform

    float acc[16];
#pragma unroll
    for (int i = 0; i < 16; ++i) acc[i] = 0.f;

    const char* fc = reinterpret_cast<const char*>(feat);

#pragma unroll
    for (int z = 0; z < Z_; ++z) {
        for (int n = 0; n < N_; ++n) {
            const int pidx = ((n * Z_ + z) * Y_ + y) * X_ + x;   // uniform
            const uint4 A = S[(size_t)pidx * 2 + 0];
            if (A.x & 0x80000000u) continue;                     // uniform skip
            const uint4 B = S[(size_t)pidx * 2 + 1];
            const unsigned dxb = ((A.x >> 30) & 1u) << 7;        // dx * 128 B
            const unsigned o00 = (A.x & 0x000FFFFFu) << 7;       // q * 128 B
            const unsigned o01 = A.y << 7;
            const unsigned o10 = A.z << 7;
            const unsigned o11 = A.w << 7;
            const float2 w0 = uph(B.x), w1 = uph(B.y), w2 = uph(B.z), w3 = uph(B.w);
            float s;
            s  = __half2float(reinterpret_cast<const __half*>(fc + o00)[lane])       * w0.x;
            s += __half2float(reinterpret_cast<const __half*>(fc + o00 + dxb)[lane]) * w0.y;
            s += __half2float(reinterpret_cast<const __half*>(fc + o01)[lane])       * w1.x;
            s += __half2float(reinterpret_cast<const __half*>(fc + o01 + dxb)[lane]) * w1.y;
            s += __half2float(reinterpret_cast<const __half*>(fc + o10)[lane])       * w2.x;
            s += __half2float(reinterpret_cast<const __half*>(fc + o10 + dxb)[lane]) * w2.y;
            s += __half2float(reinterpret_cast<const __half*>(fc + o11)[lane])       * w3.x;
            s += __half2float(reinterpret_cast<const __half*>(fc + o11 + dxb)[lane]) * w3.y;
            acc[z] += s;
        }
    }

    // Epilogue: transpose 64 points x 64 channels through LDS, write coalesced.
    __shared__ float lds[64][65];
#pragma unroll
    for (int z = 0; z < 16; ++z)
        lds[wv * 16 + z][lane] = acc[z];
    __syncthreads();
    const size_t obase = (size_t)y0 * Z_ + (size_t)x * (Y_ * Z_);
#pragma unroll
    for (int i = 0; i < 16; ++i) {
        const int c = i * 4 + wv;
        outp[(size_t)c * (X_ * Y_ * Z_) + obase + lane] = lds[lane][c];
    }
}

// ---------------------------------------------------------------------------
// Fallback (ws too small): direct fp32 gather from raw (n,c,p) layout.
// ---------------------------------------------------------------------------
__global__ __launch_bounds__(256) void k_sample_raw(const float* __restrict__ feat,
                                                    const float* __restrict__ grid,
                                                    const int* __restrict__ mask,
                                                    float* __restrict__ outp) {
    const int x    = blockIdx.x;
    const int y0   = blockIdx.y * 4;
    const int lane = threadIdx.x;
    const int wv   = threadIdx.y;
    const int y    = y0 + wv;
    float acc[16];
#pragma unroll
    for (int i = 0; i < 16; ++i) acc[i] = 0.f;
    for (int n = 0; n < N_; ++n) {
        const float* fb = feat + ((size_t)n * C_ + lane) * P_;
        for (int z = 0; z < Z_; ++z) {
            const int pidx = ((n * Z_ + z) * Y_ + y) * X_ + x;
            if (mask[pidx]) continue;
            const float* g = grid + (size_t)pidx * 3;
            const float gx = (g[0] + 1.f) * (0.5f * (D2 - 1));
            const float gy = (g[1] + 1.f) * (0.5f * (D1 - 1));
            const float gz = (g[2] + 1.f) * (0.5f * (D0 - 1));
            const float fx = floorf(gx), fy = floorf(gy), fz = floorf(gz);
            const float tx = gx - fx, ty = gy - fy, tz = gz - fz;
            const int x0 = (int)fx, y0i = (int)fy, z0i = (int)fz;
            const int x1 = x0 + 1, y1 = y0i + 1, z1 = z0i + 1;
            if (x1 < 0 || x0 > D2 - 1 || y1 < 0 || y0i > D1 - 1 ||
                z1 < 0 || z0i > D0 - 1) continue;
            const float vx0 = (x0 >= 0)      ? (1.f - tx) : 0.f;
            const float vx1 = (x1 <= D2 - 1) ? tx         : 0.f;
            const float vy0 = (y0i >= 0)     ? (1.f - ty) : 0.f;
            const float vy1 = (y1 <= D1 - 1) ? ty         : 0.f;
            const float vz0 = (z0i >= 0)     ? (1.f - tz) : 0.f;
            const float vz1 = (z1 <= D0 - 1) ? tz         : 0.f;
            const int xc0 = max(x0, 0),  xc1 = min(x1, D2 - 1);
            const int yc0 = max(y0i, 0), yc1 = min(y1, D1 - 1);
            const int zc0 = max(z0i, 0), zc1 = min(z1, D0 - 1);
            const int r00 = (zc0 * D1 + yc0) * D2;
            const int r01 = (zc0 * D1 + yc1) * D2;
            const int r10 = (zc1 * D1 + yc0) * D2;
            const int r11 = (zc1 * D1 + yc1) * D2;
            const float w00 = vz0 * vy0, w01 = vz0 * vy1;
            const float w10 = vz1 * vy0, w11 = vz1 * vy1;
            acc[z] += (fb[r00 + xc0] * vx0 + fb[r00 + xc1] * vx1) * w00
                    + (fb[r01 + xc0] * vx0 + fb[r01 + xc1] * vx1) * w01
                    + (fb[r10 + xc0] * vx0 + fb[r10 + xc1] * vx1) * w10
                    + (fb[r11 + xc0] * vx0 + fb[r11 + xc1] * vx1) * w11;
        }
    }
    __shared__ float lds[64][65];
#pragma unroll
    for (int z = 0; z < 16; ++z)
        lds[wv * 16 + z][lane] = acc[z];
    __syncthreads();
    const size_t obase = (size_t)y0 * Z_ + (size_t)x * (Y_ * Z_);
#pragma unroll
    for (int i = 0; i < 16; ++i) {
        const int c = i * 4 + wv;
        outp[(size_t)c * (X_ * Y_ * Z_) + obase + lane] = lds[lane][c];
    }
}

extern "C" void kernel_launch(void* const* d_in, const int* in_sizes, int n_in,
                              void* d_out, int out_size, void* d_ws, size_t ws_size,
                              hipStream_t stream) {
    const float* feat = (const float*)d_in[0];
    const float* grid = (const float*)d_in[1];
    const int*   mask = (const int*)d_in[2];
    float*       outp = (float*)d_out;

    const size_t featT_bytes = (size_t)N_ * P_ * C_ * sizeof(__half);  // 103.8 MB
    const size_t S_bytes     = (size_t)NP_ * 32;                       // 78.6 MB
    if (ws_size >= featT_bytes + S_bytes) {
        __half* featT = (__half*)d_ws;
        uint4*  S     = (uint4*)((char*)d_ws + featT_bytes);
        k_transpose_h<<<dim3(P_ / 64, N_), 256, 0, stream>>>(feat, featT);
        k_pre<<<NP_ / 256, 256, 0, stream>>>(grid, mask, S);
        k_sample3<<<dim3(X_, Y_ / 4), dim3(64, 4), 0, stream>>>(featT, S, outp);
    } else {
        k_sample_raw<<<dim3(X_, Y_ / 4), dim3(64, 4), 0, stream>>>(feat, grid, mask, outp);
    }
}

// Round 3
// 594.199 us; speedup vs baseline: 1.3486x; 1.0658x over previous
//
#include <hip/hip_runtime.h>
#include <hip/hip_fp16.h>

// Problem dims (fixed by setup_inputs)
constexpr int N_ = 6;            // B*N views
constexpr int C_ = 64;           // channels
constexpr int D0 = 48;           // W  (grid z-coord axis)
constexpr int D1 = 32;           // H  (grid y-coord axis)
constexpr int D2 = 88;           // D  (grid x-coord axis, innermost)
constexpr int P_ = D0 * D1 * D2; // 135168 positions per view
constexpr int Z_ = 16, Y_ = 160, X_ = 160;
constexpr int NP_ = N_ * Z_ * Y_ * X_;   // 2,457,600 sample points

constexpr int TP_BLOCKS_PER_N = P_ / 64;           // 2112
constexpr int TP_BLOCKS = TP_BLOCKS_PER_N * N_;    // 12672
constexpr int PRE_BLOCKS = NP_ / 256;              // 9600

__device__ inline unsigned pkh(float a, float b) {
    __half2 h = __floats2half2_rn(a, b);
    return *reinterpret_cast<unsigned*>(&h);
}
__device__ inline float2 uph(unsigned u) {
    __half2 h = *reinterpret_cast<__half2*>(&u);
    return __half22float2(h);
}

// ---------------------------------------------------------------------------
// Fused aux kernel.
//  blocks [0, TP_BLOCKS): transpose+convert features (n,c,p) f32 -> (n,p,c) f16
//  blocks [TP_BLOCKS, TP_BLOCKS+PRE_BLOCKS): per-point 16 B descriptor:
//    word0 = q00 | dx<<20 | dy<<21 | dz<<22 | skip<<31
//    word1 = half2(vx0, vx1);  word2 = half2(w00, w01);  word3 = half2(w10, w11)
//    where wIJ = vz_I * vy_J  (validity folded into the 1-D weights).
// ---------------------------------------------------------------------------
__global__ __launch_bounds__(256) void k_aux(const float* __restrict__ in,
                                             __half* __restrict__ out,
                                             const float* __restrict__ grid,
                                             const int* __restrict__ mask,
                                             uint4* __restrict__ S) {
    const int t = threadIdx.x;   // 0..255
    if (blockIdx.x < TP_BLOCKS) {
        __shared__ float lds[64][65];
        const int n  = blockIdx.x / TP_BLOCKS_PER_N;
        const int p0 = (blockIdx.x % TP_BLOCKS_PER_N) * 64;
        const float* ip = in + (size_t)n * C_ * P_;
        __half*      op = out + (size_t)n * P_ * C_;
        const int pq = t & 15;               // p-quad within tile
        const int cb = t >> 4;               // 0..15
#pragma unroll
        for (int i = 0; i < 4; ++i) {
            const int c = i * 16 + cb;
            const float4 v = *reinterpret_cast<const float4*>(ip + (size_t)c * P_ + p0 + pq * 4);
            lds[pq * 4 + 0][c] = v.x;
            lds[pq * 4 + 1][c] = v.y;
            lds[pq * 4 + 2][c] = v.z;
            lds[pq * 4 + 3][c] = v.w;
        }
        __syncthreads();
        const int c0 = (t & 7) * 8;
        const int pr = t >> 3;               // 0..31
#pragma unroll
        for (int i = 0; i < 2; ++i) {
            const int p = i * 32 + pr;
            uint4 u;
            u.x = pkh(lds[p][c0 + 0], lds[p][c0 + 1]);
            u.y = pkh(lds[p][c0 + 2], lds[p][c0 + 3]);
            u.z = pkh(lds[p][c0 + 4], lds[p][c0 + 5]);
            u.w = pkh(lds[p][c0 + 6], lds[p][c0 + 7]);
            *reinterpret_cast<uint4*>(op + (size_t)(p0 + p) * C_ + c0) = u;
        }
    } else {
        const int pidx = (blockIdx.x - TP_BLOCKS) * 256 + t;
        const float* g = grid + (size_t)pidx * 3;
        const float gx = (g[0] + 1.f) * (0.5f * (D2 - 1));
        const float gy = (g[1] + 1.f) * (0.5f * (D1 - 1));
        const float gz = (g[2] + 1.f) * (0.5f * (D0 - 1));
        const float fx = floorf(gx), fy = floorf(gy), fz = floorf(gz);
        const float tx = gx - fx, ty = gy - fy, tz = gz - fz;
        const int x0 = (int)fx, y0 = (int)fy, z0 = (int)fz;
        const int x1 = x0 + 1, y1 = y0 + 1, z1 = z0 + 1;
        const bool skip = (mask[pidx] != 0)
                       || x1 < 0 || x0 > D2 - 1 || y1 < 0 || y0 > D1 - 1
                       || z1 < 0 || z0 > D0 - 1;
        const float vx0 = (x0 >= 0)      ? (1.f - tx) : 0.f;
        const float vx1 = (x1 <= D2 - 1) ? tx         : 0.f;
        const float vy0 = (y0 >= 0)      ? (1.f - ty) : 0.f;
        const float vy1 = (y1 <= D1 - 1) ? ty         : 0.f;
        const float vz0 = (z0 >= 0)      ? (1.f - tz) : 0.f;
        const float vz1 = (z1 <= D0 - 1) ? tz         : 0.f;
        const int xc0 = max(x0, 0),  xc1 = min(x1, D2 - 1);
        const int yc0 = max(y0, 0),  yc1 = min(y1, D1 - 1);
        const int zc0 = max(z0, 0),  zc1 = min(z1, D0 - 1);
        const int n = pidx / (Z_ * Y_ * X_);
        const unsigned q00 = (unsigned)(n * P_) + (zc0 * D1 + yc0) * D2 + xc0;
        const unsigned dx = (unsigned)(xc1 - xc0);
        const unsigned dy = (unsigned)(yc1 - yc0);
        const unsigned dz = (unsigned)(zc1 - zc0);
        uint4 Dsc;
        Dsc.x = q00 | (dx << 20) | (dy << 21) | (dz << 22) | (skip ? 0x80000000u : 0u);
        Dsc.y = pkh(vx0, vx1);
        Dsc.z = pkh(vz0 * vy0, vz0 * vy1);
        Dsc.w = pkh(vz1 * vy0, vz1 * vy1);
        S[pidx] = Dsc;
    }
}

// ---------------------------------------------------------------------------
// Sample kernel: lane = channel, wave = one (x,y) column.  n OUTER so the
// active gather footprint is ~one view (17 MB, L2/L3-resident); z inner gives
// 16 independent accumulators.  Per active point: 1 uniform 16 B s_load,
// SALU index reconstruction, 8 coalesced 128 B fp16 gathers, 8 mixed FMAs.
// Epilogue: LDS transpose -> coalesced (C,X,Y,Z) write.
// ---------------------------------------------------------------------------
__global__ __launch_bounds__(256) void k_sample4(const __half* __restrict__ feat,
                                                 const uint4* __restrict__ S,
                                                 float* __restrict__ outp) {
    const int x    = blockIdx.x;
    const int y0   = blockIdx.y * 4;
    const int lane = threadIdx.x;      // channel
    const int wv   = threadIdx.y;      // 0..3
    const int y    = __builtin_amdgcn_readfirstlane(y0 + wv);  // wave-uniform

    float acc[16];
#pragma unroll
    for (int i = 0; i < 16; ++i) acc[i] = 0.f;

    const char* fc = reinterpret_cast<const char*>(feat);

    for (int n = 0; n < N_; ++n) {
#pragma unroll
        for (int z = 0; z < Z_; ++z) {
            const int pidx = ((n * Z_ + z) * Y_ + y) * X_ + x;   // uniform
            const uint4 A = S[pidx];
            if (A.x & 0x80000000u) continue;                     // uniform skip
            const unsigned o00 = (A.x & 0x000FFFFFu) << 7;       // q00 * 128 B
            const unsigned dxb = ((A.x >> 20) & 1u) << 7;        // +128 B
            const unsigned dyb = ((A.x >> 21) & 1u) ? (unsigned)(D2 * 128) : 0u;
            const unsigned dzb = ((A.x >> 22) & 1u) ? (unsigned)(D1 * D2 * 128) : 0u;
            const float2 wx = uph(A.y);                          // vx0, vx1
            const float2 wa = uph(A.z);                          // w00, w01
            const float2 wb = uph(A.w);                          // w10, w11
            const char* p00 = fc + o00;
            const char* p01 = p00 + dyb;
            const char* p10 = p00 + dzb;
            const char* p11 = p10 + dyb;
            float s;
            s  = __half2float(reinterpret_cast<const __half*>(p00)[lane])               * (wx.x * wa.x);
            s += __half2float(reinterpret_cast<const __half*>(p00 + dxb)[lane])         * (wx.y * wa.x);
            s += __half2float(reinterpret_cast<const __half*>(p01)[lane])               * (wx.x * wa.y);
            s += __half2float(reinterpret_cast<const __half*>(p01 + dxb)[lane])         * (wx.y * wa.y);
            s += __half2float(reinterpret_cast<const __half*>(p10)[lane])               * (wx.x * wb.x);
            s += __half2float(reinterpret_cast<const __half*>(p10 + dxb)[lane])         * (wx.y * wb.x);
            s += __half2float(reinterpret_cast<const __half*>(p11)[lane])               * (wx.x * wb.y);
            s += __half2float(reinterpret_cast<const __half*>(p11 + dxb)[lane])         * (wx.y * wb.y);
            acc[z] += s;
        }
    }

    // Epilogue: transpose 64 points x 64 channels through LDS, write coalesced.
    __shared__ float lds[64][65];
#pragma unroll
    for (int z = 0; z < 16; ++z)
        lds[wv * 16 + z][lane] = acc[z];
    __syncthreads();
    const size_t obase = (size_t)y0 * Z_ + (size_t)x * (Y_ * Z_);
#pragma unroll
    for (int i = 0; i < 16; ++i) {
        const int c = i * 4 + wv;
        outp[(size_t)c * (X_ * Y_ * Z_) + obase + lane] = lds[lane][c];
    }
}

// ---------------------------------------------------------------------------
// Fallback (ws too small): direct fp32 gather from raw (n,c,p) layout.
// ---------------------------------------------------------------------------
__global__ __launch_bounds__(256) void k_sample_raw(const float* __restrict__ feat,
                                                    const float* __restrict__ grid,
                                                    const int* __restrict__ mask,
                                                    float* __restrict__ outp) {
    const int x    = blockIdx.x;
    const int y0   = blockIdx.y * 4;
    const int lane = threadIdx.x;
    const int wv   = threadIdx.y;
    const int y    = y0 + wv;
    float acc[16];
#pragma unroll
    for (int i = 0; i < 16; ++i) acc[i] = 0.f;
    for (int n = 0; n < N_; ++n) {
        const float* fb = feat + ((size_t)n * C_ + lane) * P_;
        for (int z = 0; z < Z_; ++z) {
            const int pidx = ((n * Z_ + z) * Y_ + y) * X_ + x;
            if (mask[pidx]) continue;
            const float* g = grid + (size_t)pidx * 3;
            const float gx = (g[0] + 1.f) * (0.5f * (D2 - 1));
            const float gy = (g[1] + 1.f) * (0.5f * (D1 - 1));
            const float gz = (g[2] + 1.f) * (0.5f * (D0 - 1));
            const float fx = floorf(gx), fy = floorf(gy), fz = floorf(gz);
            const float tx = gx - fx, ty = gy - fy, tz = gz - fz;
            const int x0 = (int)fx, y0i = (int)fy, z0i = (int)fz;
            const int x1 = x0 + 1, y1 = y0i + 1, z1 = z0i + 1;
            if (x1 < 0 || x0 > D2 - 1 || y1 < 0 || y0i > D1 - 1 ||
                z1 < 0 || z0i > D0 - 1) continue;
            const float vx0 = (x0 >= 0)      ? (1.f - tx) : 0.f;
            const float vx1 = (x1 <= D2 - 1) ? tx         : 0.f;
            const float vy0 = (y0i >= 0)     ? (1.f - ty) : 0.f;
            const float vy1 = (y1 <= D1 - 1) ? ty         : 0.f;
            const float vz0 = (z0i >= 0)     ? (1.f - tz) : 0.f;
            const float vz1 = (z1 <= D0 - 1) ? tz         : 0.f;
            const int xc0 = max(x0, 0),  xc1 = min(x1, D2 - 1);
            const int yc0 = max(y0i, 0), yc1 = min(y1, D1 - 1);
            const int zc0 = max(z0i, 0), zc1 = min(z1, D0 - 1);
            const int r00 = (zc0 * D1 + yc0) * D2;
            const int r01 = (zc0 * D1 + yc1) * D2;
            const int r10 = (zc1 * D1 + yc0) * D2;
            const int r11 = (zc1 * D1 + yc1) * D2;
            const float w00 = vz0 * vy0, w01 = vz0 * vy1;
            const float w10 = vz1 * vy0, w11 = vz1 * vy1;
            acc[z] += (fb[r00 + xc0] * vx0 + fb[r00 + xc1] * vx1) * w00
                    + (fb[r01 + xc0] * vx0 + fb[r01 + xc1] * vx1) * w01
                    + (fb[r10 + xc0] * vx0 + fb[r10 + xc1] * vx1) * w10
                    + (fb[r11 + xc0] * vx0 + fb[r11 + xc1] * vx1) * w11;
        }
    }
    __shared__ float lds[64][65];
#pragma unroll
    for (int z = 0; z < 16; ++z)
        lds[wv * 16 + z][lane] = acc[z];
    __syncthreads();
    const size_t obase = (size_t)y0 * Z_ + (size_t)x * (Y_ * Z_);
#pragma unroll
    for (int i = 0; i < 16; ++i) {
        const int c = i * 4 + wv;
        outp[(size_t)c * (X_ * Y_ * Z_) + obase + lane] = lds[lane][c];
    }
}

extern "C" void kernel_launch(void* const* d_in, const int* in_sizes, int n_in,
                              void* d_out, int out_size, void* d_ws, size_t ws_size,
                              hipStream_t stream) {
    const float* feat = (const float*)d_in[0];
    const float* grid = (const float*)d_in[1];
    const int*   mask = (const int*)d_in[2];
    float*       outp = (float*)d_out;

    const size_t featT_bytes = (size_t)N_ * P_ * C_ * sizeof(__half);  // 103.8 MB
    const size_t S_bytes     = (size_t)NP_ * 16;                       // 39.3 MB
    if (ws_size >= featT_bytes + S_bytes) {
        __half* featT = (__half*)d_ws;
        uint4*  S     = (uint4*)((char*)d_ws + featT_bytes);
        k_aux<<<TP_BLOCKS + PRE_BLOCKS, 256, 0, stream>>>(feat, featT, grid, mask, S);
        k_sample4<<<dim3(X_, Y_ / 4), dim3(64, 4), 0, stream>>>(featT, S, outp);
    } else {
        k_sample_raw<<<dim3(X_, Y_ / 4), dim3(64, 4), 0, stream>>>(feat, grid, mask, outp);
    }
}